// Round 8
// baseline (2844.708 us; speedup 1.0000x reference)
//
#include <hip/hip_runtime.h>

typedef unsigned int u32;

// sizes: B=16, L=256, D=256, H=256, E=256, V=172, T=128   (all inputs f32, output f32)
// grid 256 WGs x 256 thr. g = bid&15 (batch; XCD-affine), w = bid>>4 (slice).
// WG (g,w) owns LSTM units u0=w*16..+16 (gate rows, W2 cols, W3 rows) and l-chunk w*16..+16.

// workspace layout (bytes); total ~3.5 MB
#define OFF_BAR   0ull          // u32[16*1024]  per-group monotone counters
#define OFF_STH   65536ull      // f32 [2][16][256]  ping-pong h
#define OFF_STO   98304ull      // f32 [16][256]
#define OFF_PHW2  114688ull     // f32 [16][16][256]  partial h@W2^T
#define OFF_PCTX  376832ull     // f32 [16][16][256]  partial ctx
#define OFF_PSE   638976ull     // f32 [16][16]       partial exp-sums
#define OFF_OALL  643072ull     // f32 [128][16][256] o_t per step
#define OFF_GTOK  2740224ull    // f32 [172][1024]    emb-part of gates + biases, per token

__device__ __forceinline__ float sigm(float x){ return 1.0f/(1.0f+__expf(-x)); }
__device__ __forceinline__ float tanh_f(float x){ return 1.0f - 2.0f/(1.0f+__expf(2.0f*x)); }

struct F8 { float v[8]; };
__device__ __forceinline__ F8 ld8f(const float* q){
  F8 r; float4 a = *(const float4*)q; float4 b = *(const float4*)(q+4);
  r.v[0]=a.x;r.v[1]=a.y;r.v[2]=a.z;r.v[3]=a.w;r.v[4]=b.x;r.v[5]=b.y;r.v[6]=b.z;r.v[7]=b.w;
  return r;
}
__device__ __forceinline__ float dot8(const F8& w, const float* x){
  float4 a = *(const float4*)x; float4 b = *(const float4*)(x+4);
  return w.v[0]*a.x + w.v[1]*a.y + w.v[2]*a.z + w.v[3]*a.w
       + w.v[4]*b.x + w.v[5]*b.y + w.v[6]*b.z + w.v[7]*b.w;
}
// dot of 8 register-resident weights (constant indices after unroll) with LDS vector
__device__ __forceinline__ float dot8r(const float* wr, const float* x){
  float4 a = *(const float4*)x; float4 b = *(const float4*)(x+4);
  return wr[0]*a.x + wr[1]*a.y + wr[2]*a.z + wr[3]*a.w
       + wr[4]*b.x + wr[5]*b.y + wr[6]*b.z + wr[7]*b.w;
}

// agent-scope (cross-XCD-coherent) 4B ops for cross-WG data
__device__ __forceinline__ float cohload(const float* p){
  u32 x = __hip_atomic_load((const u32*)p, __ATOMIC_RELAXED, __HIP_MEMORY_SCOPE_AGENT);
  float f; __builtin_memcpy(&f,&x,4); return f;
}
__device__ __forceinline__ void cohstore(float* p, float v){
  u32 x; __builtin_memcpy(&x,&v,4);
  __hip_atomic_store((u32*)p, x, __ATOMIC_RELAXED, __HIP_MEMORY_SCOPE_AGENT);
}

// group barrier, flush-minimal (round-7 proven): arrive = release RMW (one wbl2),
// spin = relaxed RMW polls (coherence point, no per-poll maintenance),
// exit = one acquire fence (one inv).
__device__ __forceinline__ void gbarrier(u32* cnt, u32 target){
  __syncthreads();
  if (threadIdx.x == 0){
    __hip_atomic_fetch_add(cnt, 1u, __ATOMIC_RELEASE, __HIP_MEMORY_SCOPE_AGENT);
    while (__hip_atomic_fetch_add(cnt, 0u, __ATOMIC_RELAXED, __HIP_MEMORY_SCOPE_AGENT) < target){
      __builtin_amdgcn_s_sleep(4);
    }
    __builtin_amdgcn_fence(__ATOMIC_ACQUIRE, "agent");
  }
  __syncthreads();
}

// ---------------- K0: zero barrier counters (ws is poisoned 0xAA pre-launch) ----------------
extern "C" __global__ __launch_bounds__(256)
void k_init(char* __restrict__ ws){
  u32* bar = (u32*)(ws + OFF_BAR);
  const int gt = blockIdx.x*256 + threadIdx.x;
  if (gt < 16384) bar[gt] = 0u;
}

// ---------------- K1: parallel recurrence, 16 groups x 16 WGs ----------------
extern "C" __global__ __launch_bounds__(256, 1)
void k_main(const float* __restrict__ imgs, const int* __restrict__ tgt,
            const float* __restrict__ emb,  const float* __restrict__ W_ih,
            const float* __restrict__ W_hh, const float* __restrict__ b_ih,
            const float* __restrict__ b_hh, const float* __restrict__ W1,
            const float* __restrict__ W2,   const float* __restrict__ W3,
            const float* __restrict__ beta, const float* __restrict__ whW,
            const float* __restrict__ whb,  const float* __restrict__ wcW,
            const float* __restrict__ wcb,  const float* __restrict__ woW,
            const float* __restrict__ wob,  char* __restrict__ ws)
{
  const int tid = threadIdx.x, bid = blockIdx.x;
  const int g = bid & 15, w = bid >> 4, u0 = w*16;

  u32*   bar  = (u32*)(ws + OFF_BAR) + g*1024;
  float* stH  = (float*)(ws + OFF_STH);
  float* stO  = (float*)(ws + OFF_STO);
  float* pHW2 = (float*)(ws + OFF_PHW2);
  float* pCTX = (float*)(ws + OFF_PCTX);
  float* pSE  = (float*)(ws + OFF_PSE);
  float* oAll = (float*)(ws + OFF_OALL);
  float* gtok = (float*)(ws + OFF_GTOK);

  __shared__ __align__(16) float sImg[16*256];   // own (b, l-chunk) img rows
  __shared__ __align__(16) float sEnc[16*256];   // own enc_proj rows (f32, WG-private)
  __shared__ __align__(16) float sPool[768];     // [0,256)=o  [256,512)=h  [512,768)=scratch
  __shared__ __align__(16) float sHw2[256];
  __shared__ __align__(16) float sCtx[256];
  __shared__ float sBeta[256];
  __shared__ float sG[64];
  __shared__ float sHn[16];
  __shared__ float sC[16];
  __shared__ float sE[16];
  __shared__ float sE2[16];

  sBeta[tid] = beta[tid];

  // ---- phase A: gtok[v][j] = W_ih[j][0:256]@emb[v] + b_ih[j] + b_hh[j]  (688 tasks) ----
  for (int r=0; r<3; r++){
    const int tk = bid + 256*r;
    __syncthreads();
    if (tk < 688){
      const int v = tk>>2, q = tk&3;
      sPool[512+ (tid&255)] = emb[(size_t)v*256 + tid];   // stage emb row in scratch
      __syncthreads();
      const int j = q*256 + tid;
      const float* wr = W_ih + (size_t)j*512;
      float a = 0.f;
      #pragma unroll 8
      for (int c=0; c<32; c++) a += dot8(ld8f(wr + c*8), sPool + 512 + c*8);
      gtok[(size_t)v*1024 + j] = a + b_ih[j] + b_hh[j];   // plain store; published by barrier
    } else {
      __syncthreads();
    }
  }
  __syncthreads();

  // ---- setup: stage img chunk, compute own enc_proj rows (W1 row per thread) ----
  { const size_t r0 = (size_t)(g*256 + w*16);
    for (int ri=0; ri<16; ri++) sImg[ri*256+tid] = imgs[(r0+ri)*256 + tid];
    __syncthreads();
    float acc[16];
    #pragma unroll
    for (int ri=0; ri<16; ri++) acc[ri]=0.f;
    const float* w1r = W1 + (size_t)tid*256;
    for (int c=0; c<32; c++){
      F8 wv = ld8f(w1r + c*8);
      #pragma unroll
      for (int ri=0; ri<16; ri++) acc[ri] += dot8(wv, sImg + ri*256 + c*8);
    }
    for (int ri=0; ri<16; ri++) sEnc[ri*256+tid] = acc[ri];
  }
  __syncthreads();

  // ---- init states: mean_enc (per-WG redundant), own 16 units ----
  { float m = 0.f;
    for (int l=0; l<256; l++) m += imgs[((size_t)g*256 + l)*256 + tid];
    sPool[tid] = m * (1.0f/256.0f);
  }
  __syncthreads();
  { const int j = tid>>4, sub = tid&15, u = u0 + j;
    float ah=0.f, ac=0.f, ao=0.f;
    #pragma unroll
    for (int c=0; c<2; c++){
      const size_t off = (size_t)u*256 + sub*16 + c*8;
      const float* x = sPool + sub*16 + c*8;
      ah += dot8(ld8f(whW + off), x);
      ac += dot8(ld8f(wcW + off), x);
      ao += dot8(ld8f(woW + off), x);
    }
    ah += __shfl_xor(ah,1); ah += __shfl_xor(ah,2); ah += __shfl_xor(ah,4); ah += __shfl_xor(ah,8);
    ac += __shfl_xor(ac,1); ac += __shfl_xor(ac,2); ac += __shfl_xor(ac,4); ac += __shfl_xor(ac,8);
    ao += __shfl_xor(ao,1); ao += __shfl_xor(ao,2); ao += __shfl_xor(ao,4); ao += __shfl_xor(ao,8);
    if (sub == 0){
      cohstore(stH + g*256 + u, tanhf(ah + whb[u]));   // ping buffer 0
      sC[j] = tanhf(ac + wcb[u]);                       // c-state private to owner WG
      cohstore(stO + g*256 + u, tanhf(ao + wob[u]));
    }
  }

  // ---- per-thread loop constants; weight slices -> REGISTERS (immune to buffer_inv) ----
  const int rl = tid>>2, p = tid&3;            // 64 gate-rows x 4 partial lanes
  const int unit = rl & 15, gate = rl >> 4;
  const int grow = gate*256 + u0 + unit;       // gate row in [4H], order i,f,g,o
  float wior[64], whhr[64];
  { const float* wio = W_ih + (size_t)grow*512 + 256 + p*64;
    const float* whh = W_hh + (size_t)grow*256 +       p*64;
    #pragma unroll
    for (int c=0; c<8; c++){
      F8 a = ld8f(wio + c*8);
      F8 b = ld8f(whh + c*8);
      #pragma unroll
      for (int i=0; i<8; i++){ wior[c*8+i] = a.v[i]; whhr[c*8+i] = b.v[i]; }
    }
  }
  float w2s[16];
  #pragma unroll
  for (int c=0; c<2; c++){ F8 v = ld8f(W2 + (size_t)tid*256 + u0 + c*8);
    #pragma unroll
    for (int i=0; i<8; i++) w2s[c*8+i] = v.v[i]; }
  const int j3 = tid>>4, s3 = tid&15, u3 = u0 + j3;
  float w3s[32];
  #pragma unroll
  for (int c=0; c<4; c++){ F8 v = ld8f(W3 + (size_t)u3*512 + s3*32 + c*8);
    #pragma unroll
    for (int i=0; i<8; i++) w3s[c*8+i] = v.v[i]; }
  const int* tgt_g = tgt + g*128;
  const float* gtok_row = gtok + grow;         // + y*1024 per step

  gbarrier(bar + 999, 16);   // publishes gtok + init states

  for (int t=0; t<128; t++){
    const int rdh = t&1, wrh = rdh^1;
    const int y = tgt_g[t];

    // ---- P1: stage o,h; gates from registers; LSTM pointwise; partial h@W2^T ----
    const float gyv = gtok_row[(size_t)y*1024];           // emb-part + biases (broadcast x4)
    sPool[tid]     = cohload(stO + g*256 + tid);
    sPool[256+tid] = cohload(stH + rdh*4096 + g*256 + tid);
    __syncthreads();
    { float acc = 0.f;
      const float* xo = sPool +       p*64;
      const float* xh = sPool + 256 + p*64;
      #pragma unroll
      for (int c=0; c<8; c++){
        acc += dot8r(wior + c*8, xo + c*8);
        acc += dot8r(whhr + c*8, xh + c*8);
      }
      acc += __shfl_xor(acc, 1); acc += __shfl_xor(acc, 2);
      if (p == 0) sG[rl] = acc + gyv;
    }
    __syncthreads();
    if (tid < 16){
      float ig = sG[tid], fg = sG[16+tid], gg = sG[32+tid], og = sG[48+tid];
      float cn = sigm(fg)*sC[tid] + sigm(ig)*tanh_f(gg);
      float hn = sigm(og)*tanh_f(cn);
      sC[tid] = cn; sHn[tid] = hn;
      cohstore(stH + wrh*4096 + g*256 + u0 + tid, hn);
    }
    __syncthreads();
    { float s = 0.f;
      #pragma unroll
      for (int j=0; j<16; j++) s += w2s[j] * sHn[j];
      cohstore(pHW2 + (g*16+w)*256 + tid, s);
    }
    gbarrier(bar + t*3 + 0, 16);

    // ---- P2: full hW2; scores over own l-chunk; partial ctx & expsum ----
    { float s = 0.f;
      #pragma unroll
      for (int j=0; j<16; j++) s += cohload(pHW2 + (g*16+j)*256 + tid);
      sHw2[tid] = s;
    }
    __syncthreads();
    { const int li = tid>>4, sub = tid&15;
      const float* ep = sEnc + li*256;
      float sc = 0.f;
      #pragma unroll
      for (int i=0; i<16; i++){ int d = i*16 + sub; sc += tanh_f(ep[d] + sHw2[d]) * sBeta[d]; }
      sc += __shfl_xor(sc,1); sc += __shfl_xor(sc,2); sc += __shfl_xor(sc,4); sc += __shfl_xor(sc,8);
      if (sub == 0) sE[li] = __expf(sc);   // |sc| <= sum|beta| ~ 1.3, no max-sub needed
    }
    __syncthreads();
    if (tid == 0){
      float se = 0.f;
      #pragma unroll
      for (int j=0; j<16; j++) se += sE[j];
      cohstore(pSE + g*16 + w, se);
    }
    { float c = 0.f;
      #pragma unroll
      for (int li2=0; li2<16; li2++) c += sE[li2] * sImg[li2*256 + tid];
      cohstore(pCTX + (g*16+w)*256 + tid, c);
    }
    gbarrier(bar + t*3 + 1, 16);

    // ---- P3: reduce ctx; o_new = tanh(W3 @ [h_new; ctx]) ----
    if (tid < 16) sE2[tid] = cohload(pSE + g*16 + tid);
    float cd = 0.f;
    #pragma unroll
    for (int j=0; j<16; j++) cd += cohload(pCTX + (g*16+j)*256 + tid);
    sPool[tid] = cohload(stH + wrh*4096 + g*256 + tid);   // full h_new
    __syncthreads();
    { float se = 0.f;
      #pragma unroll
      for (int j=0; j<16; j++) se += sE2[j];
      sCtx[tid] = cd / se;
    }
    __syncthreads();
    { const float* xb = (s3 < 8) ? (sPool + s3*32) : (sCtx + s3*32 - 256);
      float a = 0.f;
      #pragma unroll
      for (int c=0; c<4; c++){
        float4 xa = *(const float4*)(xb + c*8); float4 xbv = *(const float4*)(xb + c*8 + 4);
        a += w3s[c*8+0]*xa.x + w3s[c*8+1]*xa.y + w3s[c*8+2]*xa.z + w3s[c*8+3]*xa.w
           + w3s[c*8+4]*xbv.x + w3s[c*8+5]*xbv.y + w3s[c*8+6]*xbv.z + w3s[c*8+7]*xbv.w;
      }
      a += __shfl_xor(a,1); a += __shfl_xor(a,2); a += __shfl_xor(a,4); a += __shfl_xor(a,8);
      if (s3 == 0){
        float o = tanh_f(a);
        cohstore(stO + g*256 + u3, o);
        oAll[((size_t)t*16 + g)*256 + u3] = o;   // plain store; read next kernel
      }
    }
    gbarrier(bar + t*3 + 2, 16);
  }
}

// ---------------- K2: logits + softmax over all (b,t); f32 output ----------------
extern "C" __global__ __launch_bounds__(256)
void k_logits(const float* __restrict__ Wout, char* __restrict__ ws, float* __restrict__ out){
  __shared__ __align__(16) float sO_[256];
  __shared__ __align__(16) float sRed[256];
  const int tid = threadIdx.x, bid = blockIdx.x;
  const float* oAll = (const float*)(ws + OFF_OALL);
  for (int r=0; r<8; r++){
    const int q = bid*8 + r;
    const int b = q >> 7, t = q & 127;
    __syncthreads();
    sO_[tid] = oAll[((size_t)t*16 + b)*256 + tid];
    __syncthreads();
    float lg = 0.f;
    if (tid < 172){
      const float* wr = Wout + (size_t)tid*256;
      #pragma unroll 8
      for (int c=0; c<32; c++) lg += dot8(ld8f(wr + c*8), sO_ + c*8);
    }
    sRed[tid] = (tid < 172) ? lg : -1e30f;
    __syncthreads();
    for (int s2=128; s2>0; s2>>=1){ if (tid < s2) sRed[tid] = fmaxf(sRed[tid], sRed[tid+s2]); __syncthreads(); }
    const float mx = sRed[0];
    __syncthreads();
    const float ev = (tid < 172) ? __expf(lg - mx) : 0.f;
    sRed[tid] = ev;
    __syncthreads();
    for (int s2=128; s2>0; s2>>=1){ if (tid < s2) sRed[tid] += sRed[tid+s2]; __syncthreads(); }
    const float inv = 1.0f / sRed[0];
    if (tid < 172) out[((size_t)b*128 + t)*172 + tid] = ev * inv;
    __syncthreads();
  }
}

extern "C" void kernel_launch(void* const* d_in, const int* in_sizes, int n_in,
                              void* d_out, int out_size, void* d_ws, size_t ws_size,
                              hipStream_t stream) {
  (void)in_sizes; (void)n_in; (void)out_size; (void)ws_size;
  char* ws = (char*)d_ws;
  k_init<<<64, 256, 0, stream>>>(ws);
  k_main<<<256, 256, 0, stream>>>(
      (const float*)d_in[0],  (const int*)d_in[1],  (const float*)d_in[2],
      (const float*)d_in[3],  (const float*)d_in[4], (const float*)d_in[5],
      (const float*)d_in[6],  (const float*)d_in[7], (const float*)d_in[8],
      (const float*)d_in[9],  (const float*)d_in[11], (const float*)d_in[12],
      (const float*)d_in[13], (const float*)d_in[14], (const float*)d_in[15],
      (const float*)d_in[16], (const float*)d_in[17], ws);
  k_logits<<<256, 256, 0, stream>>>((const float*)d_in[10], ws, (float*)d_out);
}

// Round 9
// 2785.269 us; speedup vs baseline: 1.0213x; 1.0213x over previous
//
#include <hip/hip_runtime.h>

typedef unsigned int u32;

// sizes: B=16, L=256, D=256, H=256, E=256, V=172, T=128   (all inputs f32, output f32)
// grid 256 WGs x 256 thr. g = bid&15 (batch; XCD-affine: bids g,g+16,.. -> XCD g%8), w = bid>>4.
// WG (g,w) owns LSTM units u0=w*16..+16 (gate rows, W2 cols, W3 rows) and l-chunk w*16..+16.

// workspace layout (bytes); total ~3.8 MB
// Barrier counters: ONE PER 64B CACHELINE (slot stride 16 u32) to kill false sharing.
#define OFF_BAR   0ull          // u32 [16][6400]  per-group; slot=(t*3+ph)*16, init=6144
#define OFF_STH   409600ull     // f32 [2][16][256]  ping-pong h
#define OFF_STO   442368ull     // f32 [16][256]
#define OFF_PHW2  458752ull     // f32 [16][16][256]  partial h@W2^T
#define OFF_PCTX  720896ull     // f32 [16][16][256]  partial ctx
#define OFF_PSE   983040ull     // f32 [16][16]       partial exp-sums
#define OFF_OALL  984064ull     // f32 [128][16][256] o_t per step
#define OFF_GTOK  3081216ull    // f32 [172][1024]    emb-part of gates + biases, per token

__device__ __forceinline__ float sigm(float x){ return 1.0f/(1.0f+__expf(-x)); }
__device__ __forceinline__ float tanh_f(float x){ return 1.0f - 2.0f/(1.0f+__expf(2.0f*x)); }

struct F8 { float v[8]; };
__device__ __forceinline__ F8 ld8f(const float* q){
  F8 r; float4 a = *(const float4*)q; float4 b = *(const float4*)(q+4);
  r.v[0]=a.x;r.v[1]=a.y;r.v[2]=a.z;r.v[3]=a.w;r.v[4]=b.x;r.v[5]=b.y;r.v[6]=b.z;r.v[7]=b.w;
  return r;
}
__device__ __forceinline__ float dot8(const F8& w, const float* x){
  float4 a = *(const float4*)x; float4 b = *(const float4*)(x+4);
  return w.v[0]*a.x + w.v[1]*a.y + w.v[2]*a.z + w.v[3]*a.w
       + w.v[4]*b.x + w.v[5]*b.y + w.v[6]*b.z + w.v[7]*b.w;
}
__device__ __forceinline__ float dot8r(const float* wr, const float* x){
  float4 a = *(const float4*)x; float4 b = *(const float4*)(x+4);
  return wr[0]*a.x + wr[1]*a.y + wr[2]*a.z + wr[3]*a.w
       + wr[4]*b.x + wr[5]*b.y + wr[6]*b.z + wr[7]*b.w;
}

// agent-scope (cross-XCD-coherent) 4B ops for cross-WG data
__device__ __forceinline__ float cohload(const float* p){
  u32 x = __hip_atomic_load((const u32*)p, __ATOMIC_RELAXED, __HIP_MEMORY_SCOPE_AGENT);
  float f; __builtin_memcpy(&f,&x,4); return f;
}
__device__ __forceinline__ void cohstore(float* p, float v){
  u32 x; __builtin_memcpy(&x,&v,4);
  __hip_atomic_store((u32*)p, x, __ATOMIC_RELAXED, __HIP_MEMORY_SCOPE_AGENT);
}

// group barrier v3: arrive = release RMW (one wbl2); poll = RELAXED ATOMIC LOAD
// (concurrent read service, no RMW serialization storm); exit = one acquire fence.
// v2 (round 7/8) polled with fetch_add(0): 16 RMW pollers serialized at the MALL and
// queued ahead of arrivals -> ~6-7us/barrier. Loads don't serialize against each other.
__device__ __forceinline__ void gbarrier(u32* cnt, u32 target){
  __syncthreads();
  if (threadIdx.x == 0){
    __hip_atomic_fetch_add(cnt, 1u, __ATOMIC_RELEASE, __HIP_MEMORY_SCOPE_AGENT);
    while (__hip_atomic_load(cnt, __ATOMIC_RELAXED, __HIP_MEMORY_SCOPE_AGENT) < target){
      __builtin_amdgcn_s_sleep(1);
    }
    __builtin_amdgcn_fence(__ATOMIC_ACQUIRE, "agent");
  }
  __syncthreads();
}

// ---------------- K0: zero barrier counters (ws is poisoned 0xAA pre-launch) ----------------
extern "C" __global__ __launch_bounds__(256)
void k_init(char* __restrict__ ws){
  u32* bar = (u32*)(ws + OFF_BAR);
  const int gt = blockIdx.x*256 + threadIdx.x;
  if (gt < 102400) bar[gt] = 0u;    // 16 groups x 6400 u32
}

// ---------------- K1: parallel recurrence, 16 groups x 16 WGs ----------------
extern "C" __global__ __launch_bounds__(256, 1)
void k_main(const float* __restrict__ imgs, const int* __restrict__ tgt,
            const float* __restrict__ emb,  const float* __restrict__ W_ih,
            const float* __restrict__ W_hh, const float* __restrict__ b_ih,
            const float* __restrict__ b_hh, const float* __restrict__ W1,
            const float* __restrict__ W2,   const float* __restrict__ W3,
            const float* __restrict__ beta, const float* __restrict__ whW,
            const float* __restrict__ whb,  const float* __restrict__ wcW,
            const float* __restrict__ wcb,  const float* __restrict__ woW,
            const float* __restrict__ wob,  char* __restrict__ ws)
{
  const int tid = threadIdx.x, bid = blockIdx.x;
  const int g = bid & 15, w = bid >> 4, u0 = w*16;

  u32*   bar  = (u32*)(ws + OFF_BAR) + g*6400;   // counter slot = phase_index*16 (64B stride)
  float* stH  = (float*)(ws + OFF_STH);
  float* stO  = (float*)(ws + OFF_STO);
  float* pHW2 = (float*)(ws + OFF_PHW2);
  float* pCTX = (float*)(ws + OFF_PCTX);
  float* pSE  = (float*)(ws + OFF_PSE);
  float* oAll = (float*)(ws + OFF_OALL);
  float* gtok = (float*)(ws + OFF_GTOK);

  __shared__ __align__(16) float sImg[16*256];   // own (b, l-chunk) img rows
  __shared__ __align__(16) float sEnc[16*256];   // own enc_proj rows (f32, WG-private)
  __shared__ __align__(16) float sPool[768];     // [0,256)=o  [256,512)=h  [512,768)=scratch
  __shared__ __align__(16) float sHw2[256];
  __shared__ __align__(16) float sCtx[256];
  __shared__ float sBeta[256];
  __shared__ float sG[64];
  __shared__ float sHn[16];
  __shared__ float sC[16];
  __shared__ float sE[16];
  __shared__ float sE2[16];

  sBeta[tid] = beta[tid];

  // ---- phase A: gtok[v][j] = W_ih[j][0:256]@emb[v] + b_ih[j] + b_hh[j]  (688 tasks) ----
  for (int r=0; r<3; r++){
    const int tk = bid + 256*r;
    __syncthreads();
    if (tk < 688){
      const int v = tk>>2, q = tk&3;
      sPool[512+ (tid&255)] = emb[(size_t)v*256 + tid];   // stage emb row in scratch
      __syncthreads();
      const int j = q*256 + tid;
      const float* wr = W_ih + (size_t)j*512;
      float a = 0.f;
      #pragma unroll 8
      for (int c=0; c<32; c++) a += dot8(ld8f(wr + c*8), sPool + 512 + c*8);
      gtok[(size_t)v*1024 + j] = a + b_ih[j] + b_hh[j];   // plain store; published by barrier
    } else {
      __syncthreads();
    }
  }
  __syncthreads();

  // ---- setup: stage img chunk, compute own enc_proj rows (W1 row per thread) ----
  { const size_t r0 = (size_t)(g*256 + w*16);
    for (int ri=0; ri<16; ri++) sImg[ri*256+tid] = imgs[(r0+ri)*256 + tid];
    __syncthreads();
    float acc[16];
    #pragma unroll
    for (int ri=0; ri<16; ri++) acc[ri]=0.f;
    const float* w1r = W1 + (size_t)tid*256;
    for (int c=0; c<32; c++){
      F8 wv = ld8f(w1r + c*8);
      #pragma unroll
      for (int ri=0; ri<16; ri++) acc[ri] += dot8(wv, sImg + ri*256 + c*8);
    }
    for (int ri=0; ri<16; ri++) sEnc[ri*256+tid] = acc[ri];
  }
  __syncthreads();

  // ---- init states: mean_enc (per-WG redundant), own 16 units ----
  { float m = 0.f;
    for (int l=0; l<256; l++) m += imgs[((size_t)g*256 + l)*256 + tid];
    sPool[tid] = m * (1.0f/256.0f);
  }
  __syncthreads();
  { const int j = tid>>4, sub = tid&15, u = u0 + j;
    float ah=0.f, ac=0.f, ao=0.f;
    #pragma unroll
    for (int c=0; c<2; c++){
      const size_t off = (size_t)u*256 + sub*16 + c*8;
      const float* x = sPool + sub*16 + c*8;
      ah += dot8(ld8f(whW + off), x);
      ac += dot8(ld8f(wcW + off), x);
      ao += dot8(ld8f(woW + off), x);
    }
    ah += __shfl_xor(ah,1); ah += __shfl_xor(ah,2); ah += __shfl_xor(ah,4); ah += __shfl_xor(ah,8);
    ac += __shfl_xor(ac,1); ac += __shfl_xor(ac,2); ac += __shfl_xor(ac,4); ac += __shfl_xor(ac,8);
    ao += __shfl_xor(ao,1); ao += __shfl_xor(ao,2); ao += __shfl_xor(ao,4); ao += __shfl_xor(ao,8);
    if (sub == 0){
      cohstore(stH + g*256 + u, tanhf(ah + whb[u]));   // ping buffer 0
      sC[j] = tanhf(ac + wcb[u]);                       // c-state private to owner WG
      cohstore(stO + g*256 + u, tanhf(ao + wob[u]));
    }
  }

  // ---- per-thread loop constants; weight slices in registers ----
  const int rl = tid>>2, p = tid&3;            // 64 gate-rows x 4 partial lanes
  const int unit = rl & 15, gate = rl >> 4;
  const int grow = gate*256 + u0 + unit;       // gate row in [4H], order i,f,g,o
  float wior[64], whhr[64];
  { const float* wio = W_ih + (size_t)grow*512 + 256 + p*64;
    const float* whh = W_hh + (size_t)grow*256 +       p*64;
    #pragma unroll
    for (int c=0; c<8; c++){
      F8 a = ld8f(wio + c*8);
      F8 b = ld8f(whh + c*8);
      #pragma unroll
      for (int i=0; i<8; i++){ wior[c*8+i] = a.v[i]; whhr[c*8+i] = b.v[i]; }
    }
  }
  float w2s[16];
  #pragma unroll
  for (int c=0; c<2; c++){ F8 v = ld8f(W2 + (size_t)tid*256 + u0 + c*8);
    #pragma unroll
    for (int i=0; i<8; i++) w2s[c*8+i] = v.v[i]; }
  const int j3 = tid>>4, s3 = tid&15, u3 = u0 + j3;
  float w3s[32];
  #pragma unroll
  for (int c=0; c<4; c++){ F8 v = ld8f(W3 + (size_t)u3*512 + s3*32 + c*8);
    #pragma unroll
    for (int i=0; i<8; i++) w3s[c*8+i] = v.v[i]; }
  const int* tgt_g = tgt + g*128;
  const float* gtok_row = gtok + grow;         // + y*1024 per step

  gbarrier(bar + 6144, 16);   // publishes gtok + init states

  for (int t=0; t<128; t++){
    const int rdh = t&1, wrh = rdh^1;
    const int y = tgt_g[t];

    // ---- P1: stage o,h; gates from registers; LSTM pointwise; partial h@W2^T ----
    const float gyv = gtok_row[(size_t)y*1024];           // emb-part + biases (broadcast x4)
    sPool[tid]     = cohload(stO + g*256 + tid);
    sPool[256+tid] = cohload(stH + rdh*4096 + g*256 + tid);
    __syncthreads();
    { float acc = 0.f;
      const float* xo = sPool +       p*64;
      const float* xh = sPool + 256 + p*64;
      #pragma unroll
      for (int c=0; c<8; c++){
        acc += dot8r(wior + c*8, xo + c*8);
        acc += dot8r(whhr + c*8, xh + c*8);
      }
      acc += __shfl_xor(acc, 1); acc += __shfl_xor(acc, 2);
      if (p == 0) sG[rl] = acc + gyv;
    }
    __syncthreads();
    if (tid < 16){
      float ig = sG[tid], fg = sG[16+tid], gg = sG[32+tid], og = sG[48+tid];
      float cn = sigm(fg)*sC[tid] + sigm(ig)*tanh_f(gg);
      float hn = sigm(og)*tanh_f(cn);
      sC[tid] = cn; sHn[tid] = hn;
      cohstore(stH + wrh*4096 + g*256 + u0 + tid, hn);
    }
    __syncthreads();
    { float s = 0.f;
      #pragma unroll
      for (int j=0; j<16; j++) s += w2s[j] * sHn[j];
      cohstore(pHW2 + (g*16+w)*256 + tid, s);
    }
    gbarrier(bar + (t*3 + 0)*16, 16);

    // ---- P2: full hW2; scores over own l-chunk; partial ctx & expsum ----
    { float s = 0.f;
      #pragma unroll
      for (int j=0; j<16; j++) s += cohload(pHW2 + (g*16+j)*256 + tid);
      sHw2[tid] = s;
    }
    __syncthreads();
    { const int li = tid>>4, sub = tid&15;
      const float* ep = sEnc + li*256;
      float sc = 0.f;
      #pragma unroll
      for (int i=0; i<16; i++){ int d = i*16 + sub; sc += tanh_f(ep[d] + sHw2[d]) * sBeta[d]; }
      sc += __shfl_xor(sc,1); sc += __shfl_xor(sc,2); sc += __shfl_xor(sc,4); sc += __shfl_xor(sc,8);
      if (sub == 0) sE[li] = __expf(sc);   // |sc| <= sum|beta| ~ 1.3, no max-sub needed
    }
    __syncthreads();
    if (tid == 0){
      float se = 0.f;
      #pragma unroll
      for (int j=0; j<16; j++) se += sE[j];
      cohstore(pSE + g*16 + w, se);
    }
    { float c = 0.f;
      #pragma unroll
      for (int li2=0; li2<16; li2++) c += sE[li2] * sImg[li2*256 + tid];
      cohstore(pCTX + (g*16+w)*256 + tid, c);
    }
    gbarrier(bar + (t*3 + 1)*16, 16);

    // ---- P3: reduce ctx; o_new = tanh(W3 @ [h_new; ctx]) ----
    if (tid < 16) sE2[tid] = cohload(pSE + g*16 + tid);
    float cd = 0.f;
    #pragma unroll
    for (int j=0; j<16; j++) cd += cohload(pCTX + (g*16+j)*256 + tid);
    sPool[tid] = cohload(stH + wrh*4096 + g*256 + tid);   // full h_new
    __syncthreads();
    { float se = 0.f;
      #pragma unroll
      for (int j=0; j<16; j++) se += sE2[j];
      sCtx[tid] = cd / se;
    }
    __syncthreads();
    { const float* xb = (s3 < 8) ? (sPool + s3*32) : (sCtx + s3*32 - 256);
      float a = 0.f;
      #pragma unroll
      for (int c=0; c<4; c++){
        float4 xa = *(const float4*)(xb + c*8); float4 xbv = *(const float4*)(xb + c*8 + 4);
        a += w3s[c*8+0]*xa.x + w3s[c*8+1]*xa.y + w3s[c*8+2]*xa.z + w3s[c*8+3]*xa.w
           + w3s[c*8+4]*xbv.x + w3s[c*8+5]*xbv.y + w3s[c*8+6]*xbv.z + w3s[c*8+7]*xbv.w;
      }
      a += __shfl_xor(a,1); a += __shfl_xor(a,2); a += __shfl_xor(a,4); a += __shfl_xor(a,8);
      if (s3 == 0){
        float o = tanh_f(a);
        cohstore(stO + g*256 + u3, o);
        oAll[((size_t)t*16 + g)*256 + u3] = o;   // plain store; read next kernel
      }
    }
    gbarrier(bar + (t*3 + 2)*16, 16);
  }
}

// ---------------- K2: logits + softmax over all (b,t); f32 output ----------------
extern "C" __global__ __launch_bounds__(256)
void k_logits(const float* __restrict__ Wout, char* __restrict__ ws, float* __restrict__ out){
  __shared__ __align__(16) float sO_[256];
  __shared__ __align__(16) float sRed[256];
  const int tid = threadIdx.x, bid = blockIdx.x;
  const float* oAll = (const float*)(ws + OFF_OALL);
  for (int r=0; r<8; r++){
    const int q = bid*8 + r;
    const int b = q >> 7, t = q & 127;
    __syncthreads();
    sO_[tid] = oAll[((size_t)t*16 + b)*256 + tid];
    __syncthreads();
    float lg = 0.f;
    if (tid < 172){
      const float* wr = Wout + (size_t)tid*256;
      #pragma unroll 8
      for (int c=0; c<32; c++) lg += dot8(ld8f(wr + c*8), sO_ + c*8);
    }
    sRed[tid] = (tid < 172) ? lg : -1e30f;
    __syncthreads();
    for (int s2=128; s2>0; s2>>=1){ if (tid < s2) sRed[tid] = fmaxf(sRed[tid], sRed[tid+s2]); __syncthreads(); }
    const float mx = sRed[0];
    __syncthreads();
    const float ev = (tid < 172) ? __expf(lg - mx) : 0.f;
    sRed[tid] = ev;
    __syncthreads();
    for (int s2=128; s2>0; s2>>=1){ if (tid < s2) sRed[tid] += sRed[tid+s2]; __syncthreads(); }
    const float inv = 1.0f / sRed[0];
    if (tid < 172) out[((size_t)b*128 + t)*172 + tid] = ev * inv;
    __syncthreads();
  }
}

extern "C" void kernel_launch(void* const* d_in, const int* in_sizes, int n_in,
                              void* d_out, int out_size, void* d_ws, size_t ws_size,
                              hipStream_t stream) {
  (void)in_sizes; (void)n_in; (void)out_size; (void)ws_size;
  char* ws = (char*)d_ws;
  k_init<<<400, 256, 0, stream>>>(ws);
  k_main<<<256, 256, 0, stream>>>(
      (const float*)d_in[0],  (const int*)d_in[1],  (const float*)d_in[2],
      (const float*)d_in[3],  (const float*)d_in[4], (const float*)d_in[5],
      (const float*)d_in[6],  (const float*)d_in[7], (const float*)d_in[8],
      (const float*)d_in[9],  (const float*)d_in[11], (const float*)d_in[12],
      (const float*)d_in[13], (const float*)d_in[14], (const float*)d_in[15],
      (const float*)d_in[16], (const float*)d_in[17], ws);
  k_logits<<<256, 256, 0, stream>>>((const float*)d_in[10], ws, (float*)d_out);
}

// Round 10
// 2321.481 us; speedup vs baseline: 1.2254x; 1.1998x over previous
//
#include <hip/hip_runtime.h>

typedef unsigned int u32;

// sizes: B=16, L=256, D=256, H=256, E=256, V=172, T=128   (all inputs f32, output f32)
// grid 256 WGs x 256 thr. g = bid&15 (batch), w = bid>>4 (slice).
// WG (g,w) owns LSTM units u0=w*16..+16 (gate rows, W3 rows) and l-chunk w*16..+16.
// Sync protocol: per-WG monotone release-flag (own cacheline); consumers poll 16 flags
// in parallel lanes with relaxed loads. ALL cross-WG data goes through agent-scope
// atomics (MALL-direct), so no acquire fences are needed anywhere in the loop and
// L1/L2 stay warm for read-only data (gtok, tgt, weights).

// workspace layout (bytes)
#define OFF_BAR   0ull          // u32 [16][16][16]  flag(g,w) at g*1024B + w*64B
#define OFF_STH   65536ull      // f32 [2][16][256]  ping-pong h
#define OFF_STO   98304ull      // f32 [16][256]
#define OFF_PCTX  720896ull     // f32 [16][16][256]  partial ctx
#define OFF_PSE   983040ull     // f32 [16][16]       partial exp-sums
#define OFF_OALL  984064ull     // f32 [128][16][256] o_t per step
#define OFF_GTOK  3081216ull    // f32 [172][1024]    emb-part of gates + biases, per token

__device__ __forceinline__ float sigm(float x){ return 1.0f/(1.0f+__expf(-x)); }
__device__ __forceinline__ float tanh_f(float x){ return 1.0f - 2.0f/(1.0f+__expf(2.0f*x)); }

__device__ __forceinline__ float blo(u32 q){ u32 x = q<<16; float f; __builtin_memcpy(&f,&x,4); return f; }
__device__ __forceinline__ float bhi(u32 q){ u32 x = q & 0xffff0000u; float f; __builtin_memcpy(&f,&x,4); return f; }
__device__ __forceinline__ u32 f2bu(float f){ u32 x; __builtin_memcpy(&x,&f,4); x = x + 0x7fffu + ((x>>16)&1u); return x>>16; }

struct F8 { float v[8]; };
__device__ __forceinline__ F8 ld8f(const float* q){
  F8 r; float4 a = *(const float4*)q; float4 b = *(const float4*)(q+4);
  r.v[0]=a.x;r.v[1]=a.y;r.v[2]=a.z;r.v[3]=a.w;r.v[4]=b.x;r.v[5]=b.y;r.v[6]=b.z;r.v[7]=b.w;
  return r;
}
__device__ __forceinline__ float dot8(const F8& w, const float* x){
  float4 a = *(const float4*)x; float4 b = *(const float4*)(x+4);
  return w.v[0]*a.x + w.v[1]*a.y + w.v[2]*a.z + w.v[3]*a.w
       + w.v[4]*b.x + w.v[5]*b.y + w.v[6]*b.z + w.v[7]*b.w;
}
__device__ __forceinline__ float dot8r(const float* wr, const float* x){
  float4 a = *(const float4*)x; float4 b = *(const float4*)(x+4);
  return wr[0]*a.x + wr[1]*a.y + wr[2]*a.z + wr[3]*a.w
       + wr[4]*b.x + wr[5]*b.y + wr[6]*b.z + wr[7]*b.w;
}

// agent-scope (MALL-direct) 4B ops for all cross-WG data
__device__ __forceinline__ float cohload(const float* p){
  u32 x = __hip_atomic_load((const u32*)p, __ATOMIC_RELAXED, __HIP_MEMORY_SCOPE_AGENT);
  float f; __builtin_memcpy(&f,&x,4); return f;
}
__device__ __forceinline__ void cohstore(float* p, float v){
  u32 x; __builtin_memcpy(&x,&v,4);
  __hip_atomic_store((u32*)p, x, __ATOMIC_RELAXED, __HIP_MEMORY_SCOPE_AGENT);
}

// consumer side: lanes 0..15 poll the 16 producer flags in parallel (relaxed loads)
__device__ __forceinline__ void wait_flags(u32* gf, u32 seq){
  if (threadIdx.x < 16){
    while (__hip_atomic_load(gf + threadIdx.x*16, __ATOMIC_RELAXED, __HIP_MEMORY_SCOPE_AGENT) < seq){
      __builtin_amdgcn_s_sleep(1);
    }
  }
  __syncthreads();
}
// producer side: release-store own flag (orders prior global stores; caller must have
// drained other waves' stores via __syncthreads when they contributed data)
__device__ __forceinline__ void publish_flag(u32* myf, u32 seq){
  __hip_atomic_store(myf, seq, __ATOMIC_RELEASE, __HIP_MEMORY_SCOPE_AGENT);
}

// ---------------- K0: zero flags (ws poisoned 0xAA pre-launch) ----------------
extern "C" __global__ __launch_bounds__(256)
void k_init(char* __restrict__ ws){
  u32* bar = (u32*)(ws + OFF_BAR);
  const int gt = blockIdx.x*256 + threadIdx.x;
  if (gt < 4096) bar[gt] = 0u;
}

// ---------------- K1: parallel recurrence, 16 groups x 16 WGs ----------------
extern "C" __global__ __launch_bounds__(256, 1)
void k_main(const float* __restrict__ imgs, const int* __restrict__ tgt,
            const float* __restrict__ emb,  const float* __restrict__ W_ih,
            const float* __restrict__ W_hh, const float* __restrict__ b_ih,
            const float* __restrict__ b_hh, const float* __restrict__ W1,
            const float* __restrict__ W2,   const float* __restrict__ W3,
            const float* __restrict__ beta, const float* __restrict__ whW,
            const float* __restrict__ whb,  const float* __restrict__ wcW,
            const float* __restrict__ wcb,  const float* __restrict__ woW,
            const float* __restrict__ wob,  char* __restrict__ ws)
{
  const int tid = threadIdx.x, bid = blockIdx.x;
  const int g = bid & 15, w = bid >> 4, u0 = w*16;

  u32*   gf   = (u32*)(ws + OFF_BAR) + g*256;    // group's 16 flags, 64B apart
  u32*   myf  = gf + w*16;
  float* stH  = (float*)(ws + OFF_STH);
  float* stO  = (float*)(ws + OFF_STO);
  float* pCTX = (float*)(ws + OFF_PCTX);
  float* pSE  = (float*)(ws + OFF_PSE);
  float* oAll = (float*)(ws + OFF_OALL);
  float* gtok = (float*)(ws + OFF_GTOK);

  __shared__ __align__(16) float sImg[16*256];   // own (b, l-chunk) img rows
  __shared__ __align__(16) float sEnc[16*256];   // own enc_proj rows (WG-private)
  __shared__ __align__(16) float sPool[768];     // [0,256)=o  [256,512)=h_t  [512,768)=scratch
  __shared__ __align__(16) float sHw2[256];
  __shared__ __align__(16) float sCtx[256];
  __shared__ float sBeta[256];
  __shared__ float sG[64];
  __shared__ float sC[16];
  __shared__ float sE[16];
  __shared__ float sE2[16];

  sBeta[tid] = beta[tid];

  // ---- phase A: gtok[v][j] = W_ih[j][0:256]@emb[v] + b_ih[j] + b_hh[j]  (688 tasks) ----
  for (int r=0; r<3; r++){
    const int tk = bid + 256*r;
    __syncthreads();
    if (tk < 688){
      const int v = tk>>2, q = tk&3;
      sPool[512 + tid] = emb[(size_t)v*256 + tid];
      __syncthreads();
      const int j = q*256 + tid;
      const float* wr = W_ih + (size_t)j*512;
      float a = 0.f;
      #pragma unroll 8
      for (int c=0; c<32; c++) a += dot8(ld8f(wr + c*8), sPool + 512 + c*8);
      gtok[(size_t)v*1024 + j] = a + b_ih[j] + b_hh[j];   // plain; flushed by release-wbl2
    } else {
      __syncthreads();
    }
  }
  __syncthreads();

  // ---- setup: stage img chunk, compute own enc_proj rows ----
  { const size_t r0 = (size_t)(g*256 + w*16);
    for (int ri=0; ri<16; ri++) sImg[ri*256+tid] = imgs[(r0+ri)*256 + tid];
    __syncthreads();
    float acc[16];
    #pragma unroll
    for (int ri=0; ri<16; ri++) acc[ri]=0.f;
    const float* w1r = W1 + (size_t)tid*256;
    for (int c=0; c<32; c++){
      F8 wv = ld8f(w1r + c*8);
      #pragma unroll
      for (int ri=0; ri<16; ri++) acc[ri] += dot8(wv, sImg + ri*256 + c*8);
    }
    for (int ri=0; ri<16; ri++) sEnc[ri*256+tid] = acc[ri];
  }
  __syncthreads();

  // ---- init states: mean_enc (per-WG redundant), own 16 units ----
  { float m = 0.f;
    for (int l=0; l<256; l++) m += imgs[((size_t)g*256 + l)*256 + tid];
    sPool[tid] = m * (1.0f/256.0f);
  }
  __syncthreads();
  { const int j = tid>>4, sub = tid&15, u = u0 + j;
    float ah=0.f, ac=0.f, ao=0.f;
    #pragma unroll
    for (int c=0; c<2; c++){
      const size_t off = (size_t)u*256 + sub*16 + c*8;
      const float* x = sPool + sub*16 + c*8;
      ah += dot8(ld8f(whW + off), x);
      ac += dot8(ld8f(wcW + off), x);
      ao += dot8(ld8f(woW + off), x);
    }
    ah += __shfl_xor(ah,1); ah += __shfl_xor(ah,2); ah += __shfl_xor(ah,4); ah += __shfl_xor(ah,8);
    ac += __shfl_xor(ac,1); ac += __shfl_xor(ac,2); ac += __shfl_xor(ac,4); ac += __shfl_xor(ac,8);
    ao += __shfl_xor(ao,1); ao += __shfl_xor(ao,2); ao += __shfl_xor(ao,4); ao += __shfl_xor(ao,8);
    if (sub == 0){
      cohstore(stH + g*256 + u, tanhf(ah + whb[u]));   // ping buffer 0
      sC[j] = tanhf(ac + wcb[u]);                       // c-state private to owner WG (wave 0)
      cohstore(stO + g*256 + u, tanhf(ao + wob[u]));
    }
  }

  // ---- per-thread loop constants; weight slices in registers ----
  const int rl = tid>>2, p = tid&3;            // 64 gate-rows x 4 partial lanes
  const int unit = rl & 15, gate = rl >> 4;
  const int grow = gate*256 + u0 + unit;       // gate row in [4H], order i,f,g,o
  float wior[64], whhr[64];
  { const float* wio = W_ih + (size_t)grow*512 + 256 + p*64;
    const float* whh = W_hh + (size_t)grow*256 +       p*64;
    #pragma unroll
    for (int c=0; c<8; c++){
      F8 a = ld8f(wio + c*8);
      F8 b = ld8f(whh + c*8);
      #pragma unroll
      for (int i=0; i<8; i++){ wior[c*8+i] = a.v[i]; whhr[c*8+i] = b.v[i]; }
    }
  }
  // full W2 row d=tid as packed bf16 pairs (128 VGPRs): hW2 computed locally, no exchange
  u32 w2p[128];
  { const float* w2r = W2 + (size_t)tid*256;
    #pragma unroll
    for (int c=0; c<128; c++)
      w2p[c] = f2bu(w2r[2*c]) | (f2bu(w2r[2*c+1]) << 16);
  }
  const int j3 = tid>>4, s3 = tid&15, u3 = u0 + j3;
  float w3s[32];
  #pragma unroll
  for (int c=0; c<4; c++){ F8 v = ld8f(W3 + (size_t)u3*512 + s3*32 + c*8);
    #pragma unroll
    for (int i=0; i<8; i++) w3s[c*8+i] = v.v[i]; }
  const int* tgt_g = tgt + g*128;
  const float* gtok_row = gtok + grow;

  __syncthreads();                    // drain all waves' init stores (gtok, stH/stO)
  if (tid == 0) publish_flag(myf, 1u);   // release: wbl2 flushes dirty gtok lines

  for (int t=0; t<128; t++){
    const int rdh = t&1, wrh = rdh^1;
    const int y = tgt_g[t];                               // issue before wait (L1-warm)
    const float gyv = gtok_row[(size_t)y*1024];           // hides under poll

    // ---- P1: wait o_{t-1}; gates; LSTM pointwise; publish h_t (16 f32) ----
    wait_flags(gf, 3u*t + 1u);
    sPool[tid]     = cohload(stO + g*256 + tid);
    sPool[256+tid] = cohload(stH + rdh*4096 + g*256 + tid);
    __syncthreads();
    { float acc = 0.f;
      const float* xo = sPool +       p*64;
      const float* xh = sPool + 256 + p*64;
      #pragma unroll
      for (int c=0; c<8; c++){
        acc += dot8r(wior + c*8, xo + c*8);
        acc += dot8r(whhr + c*8, xh + c*8);
      }
      acc += __shfl_xor(acc, 1); acc += __shfl_xor(acc, 2);
      if (p == 0) sG[rl] = acc + gyv;
    }
    __syncthreads();
    if (tid < 16){
      float ig = sG[tid], fg = sG[16+tid], gg = sG[32+tid], og = sG[48+tid];
      float cn = sigm(fg)*sC[tid] + sigm(ig)*tanh_f(gg);
      float hn = sigm(og)*tanh_f(cn);
      sC[tid] = cn;
      cohstore(stH + wrh*4096 + g*256 + u0 + tid, hn);    // the h exchange (1 line)
      if (tid == 0) publish_flag(myf, 3u*t + 2u);          // same wave as h stores
    }

    // ---- P2: wait h_t; local hW2 (reg W2); scores own l's; publish ctx partial ----
    wait_flags(gf, 3u*t + 2u);
    sPool[256+tid] = cohload(stH + wrh*4096 + g*256 + tid);   // full h_t (kept for P3)
    __syncthreads();
    { const float* hb = sPool + 256;
      float a = 0.f;
      #pragma unroll
      for (int c=0; c<128; c++){
        u32 q = w2p[c];
        a += blo(q)*hb[2*c] + bhi(q)*hb[2*c+1];
      }
      sHw2[tid] = a;
    }
    __syncthreads();
    { const int li = tid>>4, sub = tid&15;
      const float* ep = sEnc + li*256;
      float sc = 0.f;
      #pragma unroll
      for (int i=0; i<16; i++){ int d = i*16 + sub; sc += tanh_f(ep[d] + sHw2[d]) * sBeta[d]; }
      sc += __shfl_xor(sc,1); sc += __shfl_xor(sc,2); sc += __shfl_xor(sc,4); sc += __shfl_xor(sc,8);
      if (sub == 0) sE[li] = __expf(sc);   // |sc| <= sum|beta| ~ 1.3, no max-sub needed
    }
    __syncthreads();
    if (tid == 0){
      float se = 0.f;
      #pragma unroll
      for (int j=0; j<16; j++) se += sE[j];
      cohstore(pSE + g*16 + w, se);
    }
    { float c = 0.f;
      #pragma unroll
      for (int li2=0; li2<16; li2++) c += sE[li2] * sImg[li2*256 + tid];
      cohstore(pCTX + (g*16+w)*256 + tid, c);
    }
    __syncthreads();                               // drain all waves' pCTX stores
    if (tid == 0) publish_flag(myf, 3u*t + 3u);

    // ---- P3: wait partials; reduce ctx; o_new = tanh(W3 @ [h_t; ctx]); publish o ----
    wait_flags(gf, 3u*t + 3u);
    if (tid < 16) sE2[tid] = cohload(pSE + g*16 + tid);
    float cd = 0.f;
    #pragma unroll
    for (int j=0; j<16; j++) cd += cohload(pCTX + (g*16+j)*256 + tid);
    __syncthreads();
    { float se = 0.f;
      #pragma unroll
      for (int j=0; j<16; j++) se += sE2[j];
      sCtx[tid] = cd / se;
    }
    __syncthreads();
    { const float* xb = (s3 < 8) ? (sPool + 256 + s3*32) : (sCtx + s3*32 - 256);
      float a = 0.f;
      #pragma unroll
      for (int c=0; c<4; c++){
        float4 xa = *(const float4*)(xb + c*8); float4 xbv = *(const float4*)(xb + c*8 + 4);
        a += w3s[c*8+0]*xa.x + w3s[c*8+1]*xa.y + w3s[c*8+2]*xa.z + w3s[c*8+3]*xa.w
           + w3s[c*8+4]*xbv.x + w3s[c*8+5]*xbv.y + w3s[c*8+6]*xbv.z + w3s[c*8+7]*xbv.w;
      }
      a += __shfl_xor(a,1); a += __shfl_xor(a,2); a += __shfl_xor(a,4); a += __shfl_xor(a,8);
      if (s3 == 0){
        float o = tanh_f(a);
        cohstore(stO + g*256 + u3, o);
        cohstore(oAll + ((size_t)t*16 + g)*256 + u3, o);   // coh: keep L2 clean for releases
      }
    }
    __syncthreads();                               // drain all waves' o stores
    if (tid == 0) publish_flag(myf, 3u*t + 4u);    // == 3(t+1)+1: next P1's wait target
  }
}

// ---------------- K2: logits + softmax over all (b,t); f32 output ----------------
extern "C" __global__ __launch_bounds__(256)
void k_logits(const float* __restrict__ Wout, char* __restrict__ ws, float* __restrict__ out){
  __shared__ __align__(16) float sO_[256];
  __shared__ __align__(16) float sRed[256];
  const int tid = threadIdx.x, bid = blockIdx.x;
  const float* oAll = (const float*)(ws + OFF_OALL);
  for (int r=0; r<8; r++){
    const int q = bid*8 + r;
    const int b = q >> 7, t = q & 127;
    __syncthreads();
    sO_[tid] = oAll[((size_t)t*16 + b)*256 + tid];
    __syncthreads();
    float lg = 0.f;
    if (tid < 172){
      const float* wr = Wout + (size_t)tid*256;
      #pragma unroll 8
      for (int c=0; c<32; c++) lg += dot8(ld8f(wr + c*8), sO_ + c*8);
    }
    sRed[tid] = (tid < 172) ? lg : -1e30f;
    __syncthreads();
    for (int s2=128; s2>0; s2>>=1){ if (tid < s2) sRed[tid] = fmaxf(sRed[tid], sRed[tid+s2]); __syncthreads(); }
    const float mx = sRed[0];
    __syncthreads();
    const float ev = (tid < 172) ? __expf(lg - mx) : 0.f;
    sRed[tid] = ev;
    __syncthreads();
    for (int s2=128; s2>0; s2>>=1){ if (tid < s2) sRed[tid] += sRed[tid+s2]; __syncthreads(); }
    const float inv = 1.0f / sRed[0];
    if (tid < 172) out[((size_t)b*128 + t)*172 + tid] = ev * inv;
    __syncthreads();
  }
}

extern "C" void kernel_launch(void* const* d_in, const int* in_sizes, int n_in,
                              void* d_out, int out_size, void* d_ws, size_t ws_size,
                              hipStream_t stream) {
  (void)in_sizes; (void)n_in; (void)out_size; (void)ws_size;
  char* ws = (char*)d_ws;
  k_init<<<16, 256, 0, stream>>>(ws);
  k_main<<<256, 256, 0, stream>>>(
      (const float*)d_in[0],  (const int*)d_in[1],  (const float*)d_in[2],
      (const float*)d_in[3],  (const float*)d_in[4], (const float*)d_in[5],
      (const float*)d_in[6],  (const float*)d_in[7], (const float*)d_in[8],
      (const float*)d_in[9],  (const float*)d_in[11], (const float*)d_in[12],
      (const float*)d_in[13], (const float*)d_in[14], (const float*)d_in[15],
      (const float*)d_in[16], (const float*)d_in[17], ws);
  k_logits<<<256, 256, 0, stream>>>((const float*)d_in[10], ws, (float*)d_out);
}